// Round 1
// baseline (315.921 us; speedup 1.0000x reference)
//
#include <hip/hip_runtime.h>

#define D_FEAT 256

// ---------------------------------------------------------------------------
// k1: deg[src[e]] += 1 over ALL edges (row-degree for gcn_norm)
// ---------------------------------------------------------------------------
__global__ void deg_count_kernel(const int* __restrict__ src, int n_edges,
                                 float* __restrict__ deg) {
    int e = blockIdx.x * blockDim.x + threadIdx.x;
    if (e < n_edges) {
        unsafeAtomicAdd(&deg[src[e]], 1.0f);
    }
}

// ---------------------------------------------------------------------------
// k2: deg -> deg^-0.5 in place (0 where deg == 0)
// ---------------------------------------------------------------------------
__global__ void deg_inv_sqrt_kernel(float* __restrict__ deg, int n_nodes) {
    int i = blockIdx.x * blockDim.x + threadIdx.x;
    if (i < n_nodes) {
        float d = deg[i];
        deg[i] = (d > 0.0f) ? rsqrtf(d) : 0.0f;
    }
}

// ---------------------------------------------------------------------------
// k3: out[i, 0:256] = x[i, :]; out[i, 256:512] = 0   (i < batch)
// float4-vectorized: 128 float4 per output row, first 64 from x, rest zero.
// ---------------------------------------------------------------------------
__global__ void init_out_kernel(const float* __restrict__ x,
                                float* __restrict__ out, int batch) {
    int idx = blockIdx.x * blockDim.x + threadIdx.x;  // over batch * 128 float4
    int row = idx >> 7;
    int j   = idx & 127;
    if (row < batch) {
        float4 v;
        if (j < 64) {
            v = ((const float4*)x)[row * 64 + j];
        } else {
            v = make_float4(0.f, 0.f, 0.f, 0.f);
        }
        ((float4*)out)[idx] = v;
    }
}

// ---------------------------------------------------------------------------
// k4: one WAVE (64 lanes) per edge. Edges with dst >= batch exit early
// (wave-uniform branch — ~80% of edges filtered, no divergence).
// Each lane handles 4 contiguous feature dims: float4 gather from x[src],
// 4 HW fp32 atomics into out[dst, 256 + lane*4 ...].
// ---------------------------------------------------------------------------
__global__ void edge_scatter_kernel(const float* __restrict__ x,
                                    const int* __restrict__ src,
                                    const int* __restrict__ dst,
                                    const float* __restrict__ dis,
                                    int n_edges, int batch,
                                    float* __restrict__ out) {
    int gtid = blockIdx.x * blockDim.x + threadIdx.x;
    int e    = gtid >> 6;      // wave index == edge index
    int lane = gtid & 63;
    if (e >= n_edges) return;

    int d = dst[e];            // wave-uniform
    if (d >= batch) return;    // wave-uniform early-out

    int s = src[e];            // wave-uniform
    float w = dis[s] * dis[d];

    float4 v = ((const float4*)(x + (size_t)s * D_FEAT))[lane];
    float* o = out + (size_t)d * (2 * D_FEAT) + D_FEAT + lane * 4;
    unsafeAtomicAdd(o + 0, w * v.x);
    unsafeAtomicAdd(o + 1, w * v.y);
    unsafeAtomicAdd(o + 2, w * v.z);
    unsafeAtomicAdd(o + 3, w * v.w);
}

// ---------------------------------------------------------------------------
extern "C" void kernel_launch(void* const* d_in, const int* in_sizes, int n_in,
                              void* d_out, int out_size, void* d_ws, size_t ws_size,
                              hipStream_t stream) {
    const float* x  = (const float*)d_in[0];
    const int*   ei = (const int*)d_in[1];

    const int n_nodes = in_sizes[0] / D_FEAT;
    const int n_edges = in_sizes[1] / 2;
    const int batch   = out_size / (2 * D_FEAT);

    const int* src = ei;            // edge_index[0]
    const int* dst = ei + n_edges;  // edge_index[1]

    float* deg = (float*)d_ws;      // n_nodes floats; becomes deg^-0.5 in place
    float* out = (float*)d_out;

    // zero the degree array (ws is poisoned to 0xAA before every launch)
    hipMemsetAsync(deg, 0, (size_t)n_nodes * sizeof(float), stream);

    deg_count_kernel<<<(n_edges + 255) / 256, 256, 0, stream>>>(src, n_edges, deg);

    deg_inv_sqrt_kernel<<<(n_nodes + 255) / 256, 256, 0, stream>>>(deg, n_nodes);

    init_out_kernel<<<(batch * 128 + 255) / 256, 256, 0, stream>>>(x, out, batch);

    // one wave per edge: n_edges * 64 threads
    long long scatter_threads = (long long)n_edges * 64;
    edge_scatter_kernel<<<(int)((scatter_threads + 255) / 256), 256, 0, stream>>>(
        x, src, dst, deg, n_edges, batch, out);
}

// Round 2
// 117.833 us; speedup vs baseline: 2.6811x; 2.6811x over previous
//
#include <hip/hip_runtime.h>

#define D_FEAT 256

// ===========================================================================
// Main path: counting-sort edges by dst, then wave-per-row register
// accumulation. No atomics on the output.
// ===========================================================================

// k1: degi[src[e]] += 1 over ALL edges; cnt[dst[e]] += 1 for dst < batch
__global__ void count_kernel(const int* __restrict__ src,
                             const int* __restrict__ dst,
                             int n_edges, int batch,
                             int* __restrict__ degi, int* __restrict__ cnt) {
    int e = blockIdx.x * blockDim.x + threadIdx.x;
    if (e < n_edges) {
        atomicAdd(&degi[src[e]], 1);
        int d = dst[e];
        if (d < batch) atomicAdd(&cnt[d], 1);
    }
}

// k2: blocks [0, rsqrt_blocks) compute dis = deg^-0.5; the last block does an
// exclusive scan of cnt[0..batch) into start[] (and a cursor[] copy).
__global__ void rsqrt_scan_kernel(const int* __restrict__ degi,
                                  float* __restrict__ dis, int n_nodes,
                                  const int* __restrict__ cnt,
                                  int* __restrict__ start,
                                  int* __restrict__ cursor,
                                  int batch, int rsqrt_blocks) {
    if ((int)blockIdx.x < rsqrt_blocks) {
        int i = blockIdx.x * blockDim.x + threadIdx.x;
        if (i < n_nodes) {
            int d = degi[i];
            dis[i] = (d > 0) ? rsqrtf((float)d) : 0.0f;
        }
        return;
    }
    // --- scan block (256 threads, batch <= 256*32) ---
    __shared__ int partials[256];
    int t = threadIdx.x;
    int per = (batch + 255) / 256;       // 16 for batch=4096
    if (per > 32) per = 32;
    int base = t * per;
    int local[32];
    int sum = 0;
    for (int j = 0; j < per; ++j) {
        int v = (base + j < batch) ? cnt[base + j] : 0;
        local[j] = sum;
        sum += v;
    }
    partials[t] = sum;
    __syncthreads();
    for (int off = 1; off < 256; off <<= 1) {
        int v = 0;
        if (t >= off) v = partials[t - off];
        __syncthreads();
        if (t >= off) partials[t] += v;
        __syncthreads();
    }
    int prefix = (t == 0) ? 0 : partials[t - 1];
    for (int j = 0; j < per; ++j) {
        if (base + j < batch) {
            int s = prefix + local[j];
            start[base + j] = s;
            cursor[base + j] = s;
        }
    }
    if (t == 255) start[batch] = partials[255];
}

// k3: bucket the relevant edges' src indices contiguously by dst
__global__ void scatter_kernel(const int* __restrict__ src,
                               const int* __restrict__ dst,
                               int n_edges, int batch,
                               int* __restrict__ cursor,
                               int* __restrict__ srcbuf) {
    int e = blockIdx.x * blockDim.x + threadIdx.x;
    if (e < n_edges) {
        int d = dst[e];
        if (d < batch) {
            int pos = atomicAdd(&cursor[d], 1);
            srcbuf[pos] = src[e];
        }
    }
}

// k4: one wave per output row. Register accumulation (float4/lane), fused
// x-copy into cols [0,256), single store of cols [256,512).
__global__ void aggregate_kernel(const float* __restrict__ x,
                                 const float* __restrict__ dis,
                                 const int* __restrict__ start,
                                 const int* __restrict__ srcbuf,
                                 int batch, float* __restrict__ out) {
    int gtid = blockIdx.x * blockDim.x + threadIdx.x;
    int r    = gtid >> 6;
    int lane = gtid & 63;
    if (r >= batch) return;

    int i  = start[r];
    int i1 = start[r + 1];
    float wd = dis[r];

    float4 acc = make_float4(0.f, 0.f, 0.f, 0.f);
    if (i < i1) {
        // 2-stage software pipeline: issue next src/dis load before
        // consuming the current row gather.
        int s = srcbuf[i];
        float w = wd * dis[s];
        const float4* xp = (const float4*)(x + (size_t)s * D_FEAT) + lane;
        for (++i; i < i1; ++i) {
            int sn = srcbuf[i];
            float4 v = *xp;
            float wn = wd * dis[sn];
            acc.x += w * v.x; acc.y += w * v.y;
            acc.z += w * v.z; acc.w += w * v.w;
            w  = wn;
            xp = (const float4*)(x + (size_t)sn * D_FEAT) + lane;
        }
        float4 v = *xp;
        acc.x += w * v.x; acc.y += w * v.y;
        acc.z += w * v.z; acc.w += w * v.w;
    }

    float4 xv = ((const float4*)(x + (size_t)r * D_FEAT))[lane];
    float4* orow = (float4*)(out + (size_t)r * (2 * D_FEAT));
    orow[lane]      = xv;   // cols [0,256)
    orow[64 + lane] = acc;  // cols [256,512)
}

// ===========================================================================
// Fallback path (ws too small): round-1 atomic scatter
// ===========================================================================
__global__ void fb_deg_count(const int* __restrict__ src, int n_edges,
                             float* __restrict__ deg) {
    int e = blockIdx.x * blockDim.x + threadIdx.x;
    if (e < n_edges) unsafeAtomicAdd(&deg[src[e]], 1.0f);
}
__global__ void fb_deg_inv_sqrt(float* __restrict__ deg, int n_nodes) {
    int i = blockIdx.x * blockDim.x + threadIdx.x;
    if (i < n_nodes) { float d = deg[i]; deg[i] = (d > 0.f) ? rsqrtf(d) : 0.f; }
}
__global__ void fb_init_out(const float* __restrict__ x, float* __restrict__ out,
                            int batch) {
    int idx = blockIdx.x * blockDim.x + threadIdx.x;
    int row = idx >> 7, j = idx & 127;
    if (row < batch) {
        float4 v = (j < 64) ? ((const float4*)x)[row * 64 + j]
                            : make_float4(0.f, 0.f, 0.f, 0.f);
        ((float4*)out)[idx] = v;
    }
}
__global__ void fb_edge_scatter(const float* __restrict__ x,
                                const int* __restrict__ src,
                                const int* __restrict__ dst,
                                const float* __restrict__ dis,
                                int n_edges, int batch, float* __restrict__ out) {
    int gtid = blockIdx.x * blockDim.x + threadIdx.x;
    int e = gtid >> 6, lane = gtid & 63;
    if (e >= n_edges) return;
    int d = dst[e];
    if (d >= batch) return;
    int s = src[e];
    float w = dis[s] * dis[d];
    float4 v = ((const float4*)(x + (size_t)s * D_FEAT))[lane];
    float* o = out + (size_t)d * (2 * D_FEAT) + D_FEAT + lane * 4;
    unsafeAtomicAdd(o + 0, w * v.x);
    unsafeAtomicAdd(o + 1, w * v.y);
    unsafeAtomicAdd(o + 2, w * v.z);
    unsafeAtomicAdd(o + 3, w * v.w);
}

// ===========================================================================
extern "C" void kernel_launch(void* const* d_in, const int* in_sizes, int n_in,
                              void* d_out, int out_size, void* d_ws, size_t ws_size,
                              hipStream_t stream) {
    const float* x  = (const float*)d_in[0];
    const int*   ei = (const int*)d_in[1];

    const int n_nodes = in_sizes[0] / D_FEAT;
    const int n_edges = in_sizes[1] / 2;
    const int batch   = out_size / (2 * D_FEAT);

    const int* src = ei;            // edge_index[0]
    const int* dst = ei + n_edges;  // edge_index[1]
    float* out = (float*)d_out;

    // ws layout (ints/floats, 4B each):
    // degi[n_nodes] | cnt[batch] | dis[n_nodes] | start[batch+1] | cursor[batch] | srcbuf[n_edges]
    size_t need = (size_t)(n_nodes + batch + n_nodes + (batch + 1) + batch + n_edges) * 4;

    if (ws_size >= need) {
        int*   degi   = (int*)d_ws;
        int*   cnt    = degi + n_nodes;
        float* dis    = (float*)(cnt + batch);
        int*   start  = (int*)(dis + n_nodes);
        int*   cursor = start + batch + 1;
        int*   srcbuf = cursor + batch;

        // zero degi + cnt (contiguous)
        hipMemsetAsync(degi, 0, (size_t)(n_nodes + batch) * 4, stream);

        int eb = (n_edges + 255) / 256;
        count_kernel<<<eb, 256, 0, stream>>>(src, dst, n_edges, batch, degi, cnt);

        int rb = (n_nodes + 255) / 256;
        rsqrt_scan_kernel<<<rb + 1, 256, 0, stream>>>(degi, dis, n_nodes,
                                                      cnt, start, cursor, batch, rb);

        scatter_kernel<<<eb, 256, 0, stream>>>(src, dst, n_edges, batch,
                                               cursor, srcbuf);

        long long th = (long long)batch * 64;
        aggregate_kernel<<<(int)((th + 255) / 256), 256, 0, stream>>>(
            x, dis, start, srcbuf, batch, out);
    } else {
        // Fallback: round-1 atomic path (needs only n_nodes floats)
        float* deg = (float*)d_ws;
        hipMemsetAsync(deg, 0, (size_t)n_nodes * sizeof(float), stream);
        fb_deg_count<<<(n_edges + 255) / 256, 256, 0, stream>>>(src, n_edges, deg);
        fb_deg_inv_sqrt<<<(n_nodes + 255) / 256, 256, 0, stream>>>(deg, n_nodes);
        fb_init_out<<<(batch * 128 + 255) / 256, 256, 0, stream>>>(x, out, batch);
        long long th = (long long)n_edges * 64;
        fb_edge_scatter<<<(int)((th + 255) / 256), 256, 0, stream>>>(
            x, src, dst, deg, n_edges, batch, out);
    }
}

// Round 3
// 99.900 us; speedup vs baseline: 3.1624x; 1.1795x over previous
//
#include <hip/hip_runtime.h>

#define D_FEAT 256
#define CAP 96   // bucket capacity per dst row; Poisson(mean 16) => P(deg>96) ~ 0

// ===========================================================================
// k1: single pass over ALL edges.
//   - degi[src[e]] += 1                     (row degree, gcn_norm)
//   - dst < batch: append src to bucket[dst] (direct-indexed, CAP slots);
//     overflow (pos >= CAP) goes to a packed (src,dst) overflow list.
// int4-vectorized: 4 edges per thread.
// ===========================================================================
__global__ __launch_bounds__(256) void edges_kernel(
        const int* __restrict__ src, const int* __restrict__ dst,
        int n_edges, int batch,
        int* __restrict__ degi, int* __restrict__ cursor,
        int* __restrict__ novf, int* __restrict__ buckets,
        long long* __restrict__ ovf) {
    int t = blockIdx.x * blockDim.x + threadIdx.x;
    int e = t * 4;
    if (e >= n_edges) return;

    int s[4], d[4];
    int rem = n_edges - e;
    if (rem >= 4) {
        int4 s4 = *(const int4*)(src + e);
        int4 d4 = *(const int4*)(dst + e);
        s[0] = s4.x; s[1] = s4.y; s[2] = s4.z; s[3] = s4.w;
        d[0] = d4.x; d[1] = d4.y; d[2] = d4.z; d[3] = d4.w;
    } else {
        for (int j = 0; j < 4; ++j) {
            s[j] = (j < rem) ? src[e + j] : 0;
            d[j] = (j < rem) ? dst[e + j] : 0x7fffffff;  // filtered out
        }
    }

#pragma unroll
    for (int j = 0; j < 4; ++j) {
        if (j < rem) atomicAdd(&degi[s[j]], 1);
        if (d[j] < batch) {
            int pos = atomicAdd(&cursor[d[j]], 1);
            if (pos < CAP) {
                buckets[(size_t)d[j] * CAP + pos] = s[j];
            } else {
                int op = atomicAdd(novf, 1);
                ovf[op] = ((long long)s[j] << 32) | (unsigned)d[j];
            }
        }
    }
}

// ===========================================================================
// k2: one wave per output row; 4 independent row-gathers in flight.
// Fused x-copy into cols [0,256), single float4 store of cols [256,512).
// Note: every bucketed s has degi[s] >= 1 (it was the src of an edge).
// ===========================================================================
__global__ __launch_bounds__(256) void aggregate_kernel(
        const float* __restrict__ x, const int* __restrict__ degi,
        const int* __restrict__ cursor, const int* __restrict__ buckets,
        int batch, float* __restrict__ out) {
    int gtid = blockIdx.x * blockDim.x + threadIdx.x;
    int r    = gtid >> 6;
    int lane = gtid & 63;
    if (r >= batch) return;

    int cnt = cursor[r];
    if (cnt > CAP) cnt = CAP;
    int dr = degi[r];
    float disr = (dr > 0) ? rsqrtf((float)dr) : 0.0f;
    const int* bk = buckets + (size_t)r * CAP;

    float4 acc = make_float4(0.f, 0.f, 0.f, 0.f);
    int i = 0;
    for (; i + 4 <= cnt; i += 4) {
        int s0 = bk[i], s1 = bk[i + 1], s2 = bk[i + 2], s3 = bk[i + 3];
        // 4 independent scalar degree loads + 4 independent float4 gathers
        int g0 = degi[s0], g1 = degi[s1], g2 = degi[s2], g3 = degi[s3];
        float4 v0 = ((const float4*)(x + (size_t)s0 * D_FEAT))[lane];
        float4 v1 = ((const float4*)(x + (size_t)s1 * D_FEAT))[lane];
        float4 v2 = ((const float4*)(x + (size_t)s2 * D_FEAT))[lane];
        float4 v3 = ((const float4*)(x + (size_t)s3 * D_FEAT))[lane];
        float w0 = disr * rsqrtf((float)g0);
        float w1 = disr * rsqrtf((float)g1);
        float w2 = disr * rsqrtf((float)g2);
        float w3 = disr * rsqrtf((float)g3);
        acc.x += w0 * v0.x + w1 * v1.x + w2 * v2.x + w3 * v3.x;
        acc.y += w0 * v0.y + w1 * v1.y + w2 * v2.y + w3 * v3.y;
        acc.z += w0 * v0.z + w1 * v1.z + w2 * v2.z + w3 * v3.z;
        acc.w += w0 * v0.w + w1 * v1.w + w2 * v2.w + w3 * v3.w;
    }
    for (; i < cnt; ++i) {
        int s0 = bk[i];
        int g0 = degi[s0];
        float4 v0 = ((const float4*)(x + (size_t)s0 * D_FEAT))[lane];
        float w0 = disr * rsqrtf((float)g0);
        acc.x += w0 * v0.x; acc.y += w0 * v0.y;
        acc.z += w0 * v0.z; acc.w += w0 * v0.w;
    }

    float4 xv = ((const float4*)(x + (size_t)r * D_FEAT))[lane];
    float4* orow = (float4*)(out + (size_t)r * (2 * D_FEAT));
    orow[lane]      = xv;   // cols [0,256)
    orow[64 + lane] = acc;  // cols [256,512)
}

// ===========================================================================
// k3: overflow fixup — one wave per overflow edge, atomic adds into out.
// Runs AFTER aggregate (aggregate does plain stores). n_ovf is ~always 0.
// ===========================================================================
__global__ __launch_bounds__(256) void fixup_kernel(
        const float* __restrict__ x, const int* __restrict__ degi,
        const int* __restrict__ novf, const long long* __restrict__ ovf,
        float* __restrict__ out) {
    int n = *novf;
    int gtid = blockIdx.x * blockDim.x + threadIdx.x;
    int w    = gtid >> 6;
    int lane = gtid & 63;
    int nw   = (gridDim.x * blockDim.x) >> 6;
    for (int e = w; e < n; e += nw) {
        long long p = ovf[e];
        int d = (int)(p & 0xffffffff);
        int s = (int)(p >> 32);
        int gr = degi[d];
        float wgt = rsqrtf((float)degi[s]) *
                    ((gr > 0) ? rsqrtf((float)gr) : 0.0f);
        float4 v = ((const float4*)(x + (size_t)s * D_FEAT))[lane];
        float* o = out + (size_t)d * (2 * D_FEAT) + D_FEAT + lane * 4;
        unsafeAtomicAdd(o + 0, wgt * v.x);
        unsafeAtomicAdd(o + 1, wgt * v.y);
        unsafeAtomicAdd(o + 2, wgt * v.z);
        unsafeAtomicAdd(o + 3, wgt * v.w);
    }
}

// ===========================================================================
// Fallback path (ws too small): atomic scatter (round-1 proven)
// ===========================================================================
__global__ void fb_deg_count(const int* __restrict__ src, int n_edges,
                             float* __restrict__ deg) {
    int e = blockIdx.x * blockDim.x + threadIdx.x;
    if (e < n_edges) unsafeAtomicAdd(&deg[src[e]], 1.0f);
}
__global__ void fb_deg_inv_sqrt(float* __restrict__ deg, int n_nodes) {
    int i = blockIdx.x * blockDim.x + threadIdx.x;
    if (i < n_nodes) { float d = deg[i]; deg[i] = (d > 0.f) ? rsqrtf(d) : 0.f; }
}
__global__ void fb_init_out(const float* __restrict__ x, float* __restrict__ out,
                            int batch) {
    int idx = blockIdx.x * blockDim.x + threadIdx.x;
    int row = idx >> 7, j = idx & 127;
    if (row < batch) {
        float4 v = (j < 64) ? ((const float4*)x)[row * 64 + j]
                            : make_float4(0.f, 0.f, 0.f, 0.f);
        ((float4*)out)[idx] = v;
    }
}
__global__ void fb_edge_scatter(const float* __restrict__ x,
                                const int* __restrict__ src,
                                const int* __restrict__ dst,
                                const float* __restrict__ dis,
                                int n_edges, int batch, float* __restrict__ out) {
    int gtid = blockIdx.x * blockDim.x + threadIdx.x;
    int e = gtid >> 6, lane = gtid & 63;
    if (e >= n_edges) return;
    int d = dst[e];
    if (d >= batch) return;
    int s = src[e];
    float w = dis[s] * dis[d];
    float4 v = ((const float4*)(x + (size_t)s * D_FEAT))[lane];
    float* o = out + (size_t)d * (2 * D_FEAT) + D_FEAT + lane * 4;
    unsafeAtomicAdd(o + 0, w * v.x);
    unsafeAtomicAdd(o + 1, w * v.y);
    unsafeAtomicAdd(o + 2, w * v.z);
    unsafeAtomicAdd(o + 3, w * v.w);
}

// ===========================================================================
extern "C" void kernel_launch(void* const* d_in, const int* in_sizes, int n_in,
                              void* d_out, int out_size, void* d_ws, size_t ws_size,
                              hipStream_t stream) {
    const float* x  = (const float*)d_in[0];
    const int*   ei = (const int*)d_in[1];

    const int n_nodes = in_sizes[0] / D_FEAT;
    const int n_edges = in_sizes[1] / 2;
    const int batch   = out_size / (2 * D_FEAT);

    const int* src = ei;            // edge_index[0]
    const int* dst = ei + n_edges;  // edge_index[1]
    float* out = (float*)d_out;

    // ws layout (4B units):
    // degi[n_nodes] | cursor[batch] | novf[1] | buckets[batch*CAP] | ovf[n_edges*2]
    size_t need = ((size_t)n_nodes + batch + 1 + (size_t)batch * CAP) * 4
                + (size_t)n_edges * 8;

    if (ws_size >= need) {
        int*       degi    = (int*)d_ws;
        int*       cursor  = degi + n_nodes;
        int*       novf    = cursor + batch;
        int*       buckets = novf + 1;
        long long* ovf     = (long long*)(buckets + (size_t)batch * CAP);

        // zero degi + cursor + novf (contiguous head of ws)
        hipMemsetAsync(degi, 0, (size_t)(n_nodes + batch + 1) * 4, stream);

        int et = (n_edges + 3) / 4;                       // 4 edges/thread
        edges_kernel<<<(et + 255) / 256, 256, 0, stream>>>(
            src, dst, n_edges, batch, degi, cursor, novf, buckets, ovf);

        long long th = (long long)batch * 64;
        aggregate_kernel<<<(int)((th + 255) / 256), 256, 0, stream>>>(
            x, degi, cursor, buckets, batch, out);

        fixup_kernel<<<64, 256, 0, stream>>>(x, degi, novf, ovf, out);
    } else {
        float* deg = (float*)d_ws;
        hipMemsetAsync(deg, 0, (size_t)n_nodes * sizeof(float), stream);
        fb_deg_count<<<(n_edges + 255) / 256, 256, 0, stream>>>(src, n_edges, deg);
        fb_deg_inv_sqrt<<<(n_nodes + 255) / 256, 256, 0, stream>>>(deg, n_nodes);
        fb_init_out<<<(batch * 128 + 255) / 256, 256, 0, stream>>>(x, out, batch);
        long long th = (long long)n_edges * 64;
        fb_edge_scatter<<<(int)((th + 255) / 256), 256, 0, stream>>>(
            x, src, dst, deg, n_edges, batch, out);
    }
}